// Round 9
// baseline (262.594 us; speedup 1.0000x reference)
//
#include <hip/hip_runtime.h>

// LSTM_WP: B=4096 batch-1 LSTMs, T=H=128, input_size=1, fused MFMA-f16 recurrence.
// Round 9: DUAL-COHORT, ZERO-DUPLICATION. r8 showed ~950 cyc/step idle from
// phase-lock (MFMA phase and trans phase serialize at the block barrier).
// Fix: 128 blocks x 32 batches. Cohort A = batches 0-15, B = 16-31, staggered:
//   [ MFMA_A(t) || ew_B(t-1) ] barrier [ MFMA_B(t) || ew_A(t) ] barrier
// Each interval a wave issues 16 dependency-free MFMAs (full M=16 tile, real
// work - unlike r7's half-wasted tiles) then the OTHER cohort's independent
// ew VALU/trans -> within-wave ILP overlaps matrix and trans pipes.
// Costs half the CUs (128 blocks); wins if interval ~= max(620,650) not sum.
// Keeps r8: exp2-domain weights (log2e folded at prep), fused-rcp ew,
// register-resident wf, compile-time LDS bases, single h-buf per cohort.

#define H   128
#define T   128
#define MB  32          // batches per block: 2 cohorts of 16
#define BLOCK 512
#define HSTRIDE 136     // f16 per h row: 272 B = 17*16 -> b128-aligned
#define XSTRIDE 36      // f32 per xs row: 144 B = 9*16 -> rows stay 16B-aligned
#define LOG2E    1.44269504088896340736f
#define TWOLOG2E 2.88539008177792681472f

typedef _Float16 f16x8 __attribute__((ext_vector_type(8)));
typedef float    f32x4 __attribute__((ext_vector_type(4)));

// ---- prep: W_hh f32 [512][128] -> f16 fragment-contiguous, log2e-pre-scaled ----
// layout: idx(ct,g,kc,q,l15) = (((ct*4+g)*4+kc)*4+q)*16+l15, 8 f16 each (16 B).
__global__ void prep_whh_kernel(const float* __restrict__ W_hh, _Float16* __restrict__ wfrag)
{
    int idx = blockIdx.x * blockDim.x + threadIdx.x;     // 0..8191
    int l15 =  idx        & 15;
    int q   = (idx >> 4)  & 3;
    int kc  = (idx >> 6)  & 3;
    int g   = (idx >> 8)  & 3;
    int ct  = (idx >> 10) & 7;
    int n  = g * H + ct * 16 + l15;                      // gate row in [0,512)
    int k0 = kc * 32 + q * 8;
    float s = (g == 2) ? TWOLOG2E : LOG2E;
    const float* src = W_hh + (size_t)n * H + k0;
    f16x8 f;
    #pragma unroll
    for (int i = 0; i < 8; ++i) f[i] = (_Float16)(src[i] * s);
    *(f16x8*)(wfrag + (size_t)idx * 8) = f;
}

__device__ __forceinline__ float frcp(float v)  { return __builtin_amdgcn_rcpf(v); }
__device__ __forceinline__ float fexp2(float v) { return __builtin_amdgcn_exp2f(v); }

// ---- one cohort's MFMA: acc = preact(t) + h_coh(t-1) @ W^T (16 MFMAs, kc-outer) ----
__device__ __forceinline__ void mfma_coh(f32x4 acc[4], const _Float16* hr,
                                         const float* xp,
                                         const f16x8 wf[4][4],
                                         const float* wihs, const float* biass,
                                         int l15, int q)
{
    const _Float16* ar = hr + l15 * HSTRIDE + q * 8;
    f16x8 af0 = *(const f16x8*)(ar);
    f16x8 af1 = *(const f16x8*)(ar + 32);
    f16x8 af2 = *(const f16x8*)(ar + 64);
    f16x8 af3 = *(const f16x8*)(ar + 96);

    float4 xl = *(const float4*)xp;     // rows b = q*4 + 0..3 of this cohort
    #pragma unroll
    for (int g = 0; g < 4; ++g) {
        f32x4 iv;
        iv[0] = fmaf(xl.x, wihs[g], biass[g]);
        iv[1] = fmaf(xl.y, wihs[g], biass[g]);
        iv[2] = fmaf(xl.z, wihs[g], biass[g]);
        iv[3] = fmaf(xl.w, wihs[g], biass[g]);
        acc[g] = __builtin_amdgcn_mfma_f32_16x16x32_f16(af0, wf[g][0], iv, 0, 0, 0);
    }
    #pragma unroll
    for (int g = 0; g < 4; ++g)
        acc[g] = __builtin_amdgcn_mfma_f32_16x16x32_f16(af1, wf[g][1], acc[g], 0, 0, 0);
    #pragma unroll
    for (int g = 0; g < 4; ++g)
        acc[g] = __builtin_amdgcn_mfma_f32_16x16x32_f16(af2, wf[g][2], acc[g], 0, 0, 0);
    #pragma unroll
    for (int g = 0; g < 4; ++g)
        acc[g] = __builtin_amdgcn_mfma_f32_16x16x32_f16(af3, wf[g][3], acc[g], 0, 0, 0);
}

// ---- one cohort's elementwise (log2 domain), 4 rows/lane, fused-rcp ----
__device__ __forceinline__ void ew_coh(const f32x4 acc[4], float* c, _Float16* hw,
                                       int q, int jcol)
{
    float Ei[4], Ef[4], Eg[4], Eo[4];
    #pragma unroll
    for (int r = 0; r < 4; ++r) {
        Ei[r] = fexp2(-acc[0][r]);       // sigmoid_i = 1/(1+Ei)
        Ef[r] = fexp2(-acc[1][r]);       // sigmoid_f = 1/(1+Ef)
        Eg[r] = fexp2( acc[2][r]);       // tanh_g    = (Eg-1)/(Eg+1)
        Eo[r] = fexp2(-acc[3][r]);       // sigmoid_o = 1/(1+Eo)
    }
    _Float16* hwp = hw + (q * 4) * HSTRIDE + jcol;
    #pragma unroll
    for (int r = 0; r < 4; ++r) {
        float u  = 1.0f + Ei[r];
        float v  = 1.0f + Ef[r];
        float w  = 1.0f + Eg[r];
        float wm = Eg[r] - 1.0f;
        float uw = u * w;
        float cn = fmaf(c[r], uw, wm * v) * frcp(v * uw);   // one rcp
        c[r] = cn;
        float Ec = fexp2(cn * TWOLOG2E); // tanh(c') = (Ec-1)/(Ec+1)
        float hv = (Ec - 1.0f) * frcp((Ec + 1.0f) * (1.0f + Eo[r]));
        hwp[r * HSTRIDE] = (_Float16)hv;
    }
}

__launch_bounds__(BLOCK, 2)
__global__ void lstm_fused_kernel(const float* __restrict__ x,
                                  const float* __restrict__ W_ih,
                                  const _Float16* __restrict__ wfrag,
                                  const float* __restrict__ b_ih,
                                  const float* __restrict__ b_hh,
                                  const float* __restrict__ fc_W,
                                  const float* __restrict__ fc_b,
                                  float* __restrict__ out)
{
    __shared__ __align__(16) float xs[T][XSTRIDE];               // 18.4 KB
    __shared__ __align__(16) _Float16 hA[16 * HSTRIDE];          // cohort A h (4.25 KB)
    __shared__ __align__(16) _Float16 hB[16 * HSTRIDE];          // cohort B h

    const int tid  = threadIdx.x;
    const int wave = tid >> 6;          // column tile 0..7
    const int lane = tid & 63;
    const int l15  = lane & 15;
    const int q    = lane >> 4;         // 0..3
    const int jcol = wave * 16 + l15;   // hidden column 0..127

    // ---- stage x: 32 batches x 128 t -> xs[t][b] (coalesced reads per i) ----
    {
        const int t0 = tid & 127;
        const int b0 = tid >> 7;        // 0..3
        const float* xb = x + (size_t)blockIdx.x * (MB * T);
        #pragma unroll
        for (int i = 0; i < 8; ++i) {
            const int b = b0 + 4 * i;   // 0..31
            xs[t0][b] = xb[b * T + t0];
        }
    }
    for (int i = tid; i < 16 * HSTRIDE; i += BLOCK) {            // h0 = 0, both cohorts
        hA[i] = (_Float16)0.0f;
        hB[i] = (_Float16)0.0f;
    }

    // ---- weights: this wave's 16 gate-cols as f16 fragments (64 VGPRs) ----
    f16x8 wf[4][4];
    float wihs[4], biass[4];
    {
        const _Float16* wbase = wfrag + (size_t)wave * 8192;
        #pragma unroll
        for (int g = 0; g < 4; ++g) {
            const int n = g * H + jcol;
            const float s = (g == 2) ? TWOLOG2E : LOG2E;
            wihs[g]  = W_ih[n] * s;
            biass[g] = (b_ih[n] + b_hh[n]) * s;
            #pragma unroll
            for (int kc = 0; kc < 4; ++kc)
                wf[g][kc] = *(const f16x8*)(wbase + ((((g * 4 + kc) * 4 + q) * 16 + l15) * 8));
        }
    }

    float cA[4] = {0.f, 0.f, 0.f, 0.f};
    float cB[4] = {0.f, 0.f, 0.f, 0.f};
    f32x4 accA[4], accB[4];
    const int xq = q * 4;

    __syncthreads();

    // ---- prologue ----
    mfma_coh(accA, hA, &xs[0][xq], wf, wihs, biass, l15, q);          // A(0)
    __syncthreads();
    mfma_coh(accB, hB, &xs[0][16 + xq], wf, wihs, biass, l15, q);     // B(0)
    ew_coh(accA, cA, hA, q, jcol);                                    // ew_A(0)
    __syncthreads();

    // ---- steady state: B lags half an interval ----
    #pragma unroll 1
    for (int t = 1; t < T; ++t) {
        mfma_coh(accA, hA, &xs[t][xq], wf, wihs, biass, l15, q);      // MFMA_A(t)
        ew_coh(accB, cB, hB, q, jcol);                                // ew_B(t-1) [independent]
        __syncthreads();
        mfma_coh(accB, hB, &xs[t][16 + xq], wf, wihs, biass, l15, q); // MFMA_B(t)
        ew_coh(accA, cA, hA, q, jcol);                                // ew_A(t)   [independent]
        __syncthreads();
    }
    ew_coh(accB, cB, hB, q, jcol);                                    // ew_B(T-1)
    __syncthreads();

    // ---- epilogue: out[b] = fc_b + sum_j fc_W[j] * hT[b][j] ----
    {
        const int b    = tid >> 4;      // 0..31
        const int part = tid & 15;
        const _Float16* hrow = (b < 16) ? &hA[b * HSTRIDE] : &hB[(b - 16) * HSTRIDE];
        float s = 0.0f;
        #pragma unroll
        for (int i = 0; i < 8; ++i) {
            const int j = part * 8 + i;
            s += fc_W[j] * (float)hrow[j];
        }
        s += __shfl_xor(s, 8, 16);
        s += __shfl_xor(s, 4, 16);
        s += __shfl_xor(s, 2, 16);
        s += __shfl_xor(s, 1, 16);
        if (part == 0)
            out[blockIdx.x * MB + b] = s + fc_b[0];
    }
}

extern "C" void kernel_launch(void* const* d_in, const int* in_sizes, int n_in,
                              void* d_out, int out_size, void* d_ws, size_t ws_size,
                              hipStream_t stream)
{
    const float* x    = (const float*)d_in[0];
    const float* W_ih = (const float*)d_in[1];
    const float* W_hh = (const float*)d_in[2];
    const float* b_ih = (const float*)d_in[3];
    const float* b_hh = (const float*)d_in[4];
    const float* fc_W = (const float*)d_in[5];
    const float* fc_b = (const float*)d_in[6];
    float* out = (float*)d_out;

    _Float16* wfrag = (_Float16*)d_ws;     // 64K f16 = 128 KB fragment-ordered, log2e-scaled

    hipLaunchKernelGGL(prep_whh_kernel, dim3(32), dim3(256), 0, stream, W_hh, wfrag);

    const int B = in_sizes[0] / H;         // 4096 chunks
    dim3 grid(B / MB);                     // 128 blocks -> <=1 per CU (half chip, zero dup)
    dim3 block(BLOCK);                     // 8 waves, 2 per SIMD
    hipLaunchKernelGGL(lstm_fused_kernel, grid, block, 0, stream,
                       x, W_ih, wfrag, b_ih, b_hh, fc_W, fc_b, out);
}

// Round 10
// 168.710 us; speedup vs baseline: 1.5565x; 1.5565x over previous
//
#include <hip/hip_runtime.h>

// LSTM_WP: B=4096 batch-1 LSTMs, T=H=128, input_size=1, fused MFMA-f16 recurrence.
// Round 10: r8 skeleton (proven fastest; 1 barrier/step, zero duplication,
// 256 blocks x 16 batches, 8 waves) + critical-path surgery:
//  (1) MFMA split into 8 independent depth-2 chains (lo: kc0,kc1 seeded with
//      preact; hi: kc2,kc3 seeded with 0), merged by 4 vector adds -> cuts the
//      exposed MFMA dependency tail before ew's waitcnt.
//  (2) preact iv(t+1) computed inside step t's MFMA/exp shadow (depends only
//      on xs) -> removes 16 fma + an LDS read from the post-barrier window.
// Design-space note: full-chip + zero-dup + >2 waves/SIMD is combinatorially
// impossible (4096 = 256 CU x one M=16 tile); r2/r5/r6/r7/r9 each paid
// duplication or CU idling for overlap and all regressed.

#define H   128
#define T   128
#define BLOCK 512
#define HSTRIDE 136     // f16 per h row: 272 B -> b128-aligned, 2-way banks (free)
#define XSTRIDE 20      // f32 per xs row: 80 B, b128-aligned float4 reads
#define LOG2E    1.44269504088896340736f
#define TWOLOG2E 2.88539008177792681472f

typedef _Float16 f16x8 __attribute__((ext_vector_type(8)));
typedef float    f32x4 __attribute__((ext_vector_type(4)));

// ---- prep: W_hh f32 [512][128] -> f16 fragment-contiguous, log2e-pre-scaled ----
// layout: idx(ct,g,kc,q,l15) = (((ct*4+g)*4+kc)*4+q)*16+l15, 8 f16 each (16 B).
__global__ void prep_whh_kernel(const float* __restrict__ W_hh, _Float16* __restrict__ wfrag)
{
    int idx = blockIdx.x * blockDim.x + threadIdx.x;     // 0..8191
    int l15 =  idx        & 15;
    int q   = (idx >> 4)  & 3;
    int kc  = (idx >> 6)  & 3;
    int g   = (idx >> 8)  & 3;
    int ct  = (idx >> 10) & 7;
    int n  = g * H + ct * 16 + l15;                      // gate row in [0,512)
    int k0 = kc * 32 + q * 8;
    float s = (g == 2) ? TWOLOG2E : LOG2E;
    const float* src = W_hh + (size_t)n * H + k0;
    f16x8 f;
    #pragma unroll
    for (int i = 0; i < 8; ++i) f[i] = (_Float16)(src[i] * s);
    *(f16x8*)(wfrag + (size_t)idx * 8) = f;
}

__device__ __forceinline__ float frcp(float v)  { return __builtin_amdgcn_rcpf(v); }
__device__ __forceinline__ float fexp2(float v) { return __builtin_amdgcn_exp2f(v); }

// ---- one LSTM step for 16 batches x this wave's 16 cols ----
// iv: preacts for THIS step (in); refilled with preacts for the NEXT step (out).
__device__ __forceinline__ void lstm_step(const _Float16* hr, _Float16* hw,
                                          f32x4 iv[4], const float* xp_next,
                                          const f16x8 wf[4][4],
                                          const float* wihs, const float* biass,
                                          float* c, int l15, int q, int jcol)
{
    // A-fragments: m(batch)=l15, k = kc*32 + q*8 + i (4x ds_read_b128, imm offsets)
    const _Float16* ar = hr + l15 * HSTRIDE + q * 8;
    f16x8 af0 = *(const f16x8*)(ar);
    f16x8 af1 = *(const f16x8*)(ar + 32);
    f16x8 af2 = *(const f16x8*)(ar + 64);
    f16x8 af3 = *(const f16x8*)(ar + 96);

    // 8 independent depth-2 MFMA chains: lo = kc0,kc1 (C=preact), hi = kc2,kc3 (C=0)
    const f32x4 zz = {0.f, 0.f, 0.f, 0.f};
    f32x4 lo[4], hi[4];
    #pragma unroll
    for (int g = 0; g < 4; ++g)
        lo[g] = __builtin_amdgcn_mfma_f32_16x16x32_f16(af0, wf[g][0], iv[g], 0, 0, 0);
    #pragma unroll
    for (int g = 0; g < 4; ++g)
        hi[g] = __builtin_amdgcn_mfma_f32_16x16x32_f16(af2, wf[g][2], zz, 0, 0, 0);
    #pragma unroll
    for (int g = 0; g < 4; ++g)
        lo[g] = __builtin_amdgcn_mfma_f32_16x16x32_f16(af1, wf[g][1], lo[g], 0, 0, 0);
    #pragma unroll
    for (int g = 0; g < 4; ++g)
        hi[g] = __builtin_amdgcn_mfma_f32_16x16x32_f16(af3, wf[g][3], hi[g], 0, 0, 0);

    // next step's preacts: xs-only dependence -> issues in the MFMA shadow
    {
        float4 xl = *(const float4*)xp_next;
        #pragma unroll
        for (int g = 0; g < 4; ++g) {
            iv[g][0] = fmaf(xl.x, wihs[g], biass[g]);
            iv[g][1] = fmaf(xl.y, wihs[g], biass[g]);
            iv[g][2] = fmaf(xl.z, wihs[g], biass[g]);
            iv[g][3] = fmaf(xl.w, wihs[g], biass[g]);
        }
    }

    // merge halves (4 vector adds), then ew
    f32x4 acc[4];
    #pragma unroll
    for (int g = 0; g < 4; ++g)
        acc[g] = lo[g] + hi[g];

    // ---- ew phase 1: all 16 independent exps (log2 domain, saturate trans pipe) ----
    float Ei[4], Ef[4], Eg[4], Eo[4];
    #pragma unroll
    for (int r = 0; r < 4; ++r) {
        Ei[r] = fexp2(-acc[0][r]);       // sigmoid_i = 1/(1+Ei)
        Ef[r] = fexp2(-acc[1][r]);       // sigmoid_f = 1/(1+Ef)
        Eg[r] = fexp2( acc[2][r]);       // tanh_g    = (Eg-1)/(Eg+1)
        Eo[r] = fexp2(-acc[3][r]);       // sigmoid_o = 1/(1+Eo)
    }
    // ---- ew phase 2: fused-rcp c/h updates + dependent tanh(c) exps ----
    _Float16* hwp = hw + (q * 4) * HSTRIDE + jcol;
    #pragma unroll
    for (int r = 0; r < 4; ++r) {
        float u  = 1.0f + Ei[r];
        float v  = 1.0f + Ef[r];
        float w  = 1.0f + Eg[r];
        float wm = Eg[r] - 1.0f;
        float uw = u * w;
        // c' = c/v + wm/(u*w) = [c*u*w + wm*v] / (v*u*w), one rcp
        float cn = fmaf(c[r], uw, wm * v) * frcp(v * uw);
        c[r] = cn;
        float Ec = fexp2(cn * TWOLOG2E); // tanh(c') = (Ec-1)/(Ec+1)
        float hv = (Ec - 1.0f) * frcp((Ec + 1.0f) * (1.0f + Eo[r]));
        hwp[r * HSTRIDE] = (_Float16)hv;
    }
}

__launch_bounds__(BLOCK, 2)
__global__ void lstm_fused_kernel(const float* __restrict__ x,
                                  const float* __restrict__ W_ih,
                                  const _Float16* __restrict__ wfrag,
                                  const float* __restrict__ b_ih,
                                  const float* __restrict__ b_hh,
                                  const float* __restrict__ fc_W,
                                  const float* __restrict__ fc_b,
                                  float* __restrict__ out)
{
    __shared__ __align__(16) float xs[T + 1][XSTRIDE];           // +1 row: prefetch pad
    __shared__ __align__(16) _Float16 hb0[16 * HSTRIDE];         // h buffers (4.25 KB each)
    __shared__ __align__(16) _Float16 hb1[16 * HSTRIDE];

    const int tid  = threadIdx.x;
    const int wave = tid >> 6;          // column tile 0..7
    const int lane = tid & 63;
    const int l15  = lane & 15;
    const int q    = lane >> 4;         // 0..3
    const int jcol = wave * 16 + l15;   // hidden column 0..127

    // ---- stage x: [b][t] global -> xs[t][b] (16 batches x 128 t) ----
    {
        const int t0 = tid & 127;
        const int bb = tid >> 7;        // 0..3
        const float* xb = x + (size_t)blockIdx.x * (16 * T);
        xs[t0][bb]      = xb[bb * T + t0];
        xs[t0][bb + 4]  = xb[(bb + 4) * T + t0];
        xs[t0][bb + 8]  = xb[(bb + 8) * T + t0];
        xs[t0][bb + 12] = xb[(bb + 12) * T + t0];
    }
    for (int i = tid; i < 16 * HSTRIDE; i += BLOCK)              // h0 = 0
        hb0[i] = (_Float16)0.0f;

    // ---- weights: this wave's 16 gate-cols as f16 fragments (64 VGPRs) ----
    f16x8 wf[4][4];
    float wihs[4], biass[4];
    {
        const _Float16* wbase = wfrag + (size_t)wave * 8192;
        #pragma unroll
        for (int g = 0; g < 4; ++g) {
            const int n = g * H + jcol;
            const float s = (g == 2) ? TWOLOG2E : LOG2E;
            wihs[g]  = W_ih[n] * s;
            biass[g] = (b_ih[n] + b_hh[n]) * s;
            #pragma unroll
            for (int kc = 0; kc < 4; ++kc)
                wf[g][kc] = *(const f16x8*)(wbase + ((((g * 4 + kc) * 4 + q) * 16 + l15) * 8));
        }
    }

    float c[4] = {0.f, 0.f, 0.f, 0.f};

    __syncthreads();

    // preacts for t=0 (xs is staged)
    f32x4 iv[4];
    {
        float4 xl = *(const float4*)&xs[0][q * 4];
        #pragma unroll
        for (int g = 0; g < 4; ++g) {
            iv[g][0] = fmaf(xl.x, wihs[g], biass[g]);
            iv[g][1] = fmaf(xl.y, wihs[g], biass[g]);
            iv[g][2] = fmaf(xl.z, wihs[g], biass[g]);
            iv[g][3] = fmaf(xl.w, wihs[g], biass[g]);
        }
    }
    const float* xpn = &xs[1][q * 4];   // next-step preact source

    // ---- recurrence: unrolled x2, compile-time buffer bases, 1 barrier/step ----
    #pragma unroll 1
    for (int t2 = 0; t2 < T / 2; ++t2) {
        lstm_step(hb0, hb1, iv, xpn, wf, wihs, biass, c, l15, q, jcol);
        xpn += XSTRIDE;
        __syncthreads();
        lstm_step(hb1, hb0, iv, xpn, wf, wihs, biass, c, l15, q, jcol);
        xpn += XSTRIDE;
        __syncthreads();
    }
    // T even -> final h lives in hb0

    // ---- epilogue: out[b] = fc_b + sum_j fc_W[j] * hT[b][j] ----
    if (tid < 256) {
        const int b    = tid >> 4;      // 0..15
        const int part = tid & 15;
        const _Float16* hrow = &hb0[b * HSTRIDE];
        float s = 0.0f;
        #pragma unroll
        for (int i = 0; i < 8; ++i) {
            const int j = part * 8 + i;
            s += fc_W[j] * (float)hrow[j];
        }
        s += __shfl_xor(s, 8, 16);
        s += __shfl_xor(s, 4, 16);
        s += __shfl_xor(s, 2, 16);
        s += __shfl_xor(s, 1, 16);
        if (part == 0)
            out[blockIdx.x * 16 + b] = s + fc_b[0];
    }
}

extern "C" void kernel_launch(void* const* d_in, const int* in_sizes, int n_in,
                              void* d_out, int out_size, void* d_ws, size_t ws_size,
                              hipStream_t stream)
{
    const float* x    = (const float*)d_in[0];
    const float* W_ih = (const float*)d_in[1];
    const float* W_hh = (const float*)d_in[2];
    const float* b_ih = (const float*)d_in[3];
    const float* b_hh = (const float*)d_in[4];
    const float* fc_W = (const float*)d_in[5];
    const float* fc_b = (const float*)d_in[6];
    float* out = (float*)d_out;

    _Float16* wfrag = (_Float16*)d_ws;     // 64K f16 = 128 KB fragment-ordered, log2e-scaled

    hipLaunchKernelGGL(prep_whh_kernel, dim3(32), dim3(256), 0, stream, W_hh, wfrag);

    const int B = in_sizes[0] / H;         // 4096 chunks
    dim3 grid(B / 16);                     // 256 blocks -> 1 per CU
    dim3 block(BLOCK);                     // 8 waves, 2 per SIMD
    hipLaunchKernelGGL(lstm_fused_kernel, grid, block, 0, stream,
                       x, W_ih, wfrag, b_ih, b_hh, fc_W, fc_b, out);
}